// Round 5
// baseline (161.501 us; speedup 1.0000x reference)
//
#include <hip/hip_runtime.h>
#include <hip/hip_bf16.h>

// s[256] = weight_b[256,20] @ tag[20]
// shared_w = (weight_a[8192,256] * s[None,:]) @ weight_c[256,2048] -> out rows 0..8191
// rows 8192..10239 = individual_weight[2048,2048]; tail: bias[8192], individual_bias[2048]
// Output dtype: FLOAT32 (reference returns f32; harness doc: "else float*").
// Internal GEMM in bf16 MFMA (threshold = 2% of max|ref| = 2.87e-3; bf16 noise ~2.5e-4).

typedef __attribute__((ext_vector_type(8))) short short8;
typedef __attribute__((ext_vector_type(4))) float floatx4;

#define M_TOT 8192
#define N_TOT 2048
#define K_TOT 256
#define BM 128
#define BN 128
#define BK 32
#define APAD 40   // padded LDS row (elems): 2-way bank conflict only

__device__ inline ushort f2bf(float x) {
    union { float f; unsigned u; } v; v.f = x;
    unsigned r = v.u + 0x7fffu + ((v.u >> 16) & 1u);   // RNE
    return (ushort)(r >> 16);
}

__global__ __launch_bounds__(256)
void gemm_shared_w(const float* __restrict__ Wa, const float* __restrict__ Wc,
                   const float* __restrict__ Wb, const float* __restrict__ tag,
                   float* __restrict__ out)
{
    __shared__ float s_sm[K_TOT];
    __shared__ ushort As[BM * APAD];
    __shared__ ushort Bs[BN * APAD];

    const int tid = threadIdx.x;
    const int bn = blockIdx.x;   // 0..15
    const int bm = blockIdx.y;   // 0..63

    // s = Wb @ tag
    {
        float sv = 0.f;
        const float* wb = Wb + tid * 20;
        #pragma unroll
        for (int j = 0; j < 20; ++j) sv += wb[j] * tag[j];
        s_sm[tid] = sv;
    }

    const int lane = tid & 63;
    const int wave = tid >> 6;
    const int wm = (wave >> 1) * 64;
    const int wn = (wave & 1) * 64;
    const int lrow = lane & 15;
    const int lk   = (lane >> 4) * 8;

    const int ar  = tid >> 3;   // A row group
    const int akq = tid & 7;    // A k-quad
    const int bk  = tid >> 5;   // B k row
    const int bnq = tid & 31;   // B n-quad

    const float* Abase = Wa + (size_t)(bm * BM) * K_TOT;
    const float* Bbase = Wc + bn * BN;

    floatx4 acc[4][4] = {};

    for (int kt = 0; kt < K_TOT / BK; ++kt) {
        __syncthreads();   // prev-iter LDS reads done; iter0: s_sm ready

        const float4 sv4 = *reinterpret_cast<const float4*>(&s_sm[kt * BK + akq * 4]);
        #pragma unroll
        for (int rr = 0; rr < 4; ++rr) {
            const int row = ar + rr * 32;
            const float4 a = *reinterpret_cast<const float4*>(Abase + (size_t)row * K_TOT + kt * BK + akq * 4);
            ushort4 p;
            p.x = f2bf(a.x * sv4.x);
            p.y = f2bf(a.y * sv4.y);
            p.z = f2bf(a.z * sv4.z);
            p.w = f2bf(a.w * sv4.w);
            *reinterpret_cast<ushort4*>(&As[row * APAD + akq * 4]) = p;
        }

        #pragma unroll
        for (int kk = 0; kk < 4; ++kk) {
            const int k = bk + kk * 8;
            const float4 b = *reinterpret_cast<const float4*>(Bbase + (size_t)(kt * BK + k) * N_TOT + bnq * 4);
            Bs[(bnq * 4 + 0) * APAD + k] = f2bf(b.x);
            Bs[(bnq * 4 + 1) * APAD + k] = f2bf(b.y);
            Bs[(bnq * 4 + 2) * APAD + k] = f2bf(b.z);
            Bs[(bnq * 4 + 3) * APAD + k] = f2bf(b.w);
        }

        __syncthreads();

        short8 af[4], bfr[4];
        #pragma unroll
        for (int i = 0; i < 4; ++i)
            af[i] = *reinterpret_cast<const short8*>(&As[(wm + i * 16 + lrow) * APAD + lk]);
        #pragma unroll
        for (int i = 0; i < 4; ++i)
            bfr[i] = *reinterpret_cast<const short8*>(&Bs[(wn + i * 16 + lrow) * APAD + lk]);

        #pragma unroll
        for (int mi = 0; mi < 4; ++mi)
            #pragma unroll
            for (int ni = 0; ni < 4; ++ni)
                acc[mi][ni] = __builtin_amdgcn_mfma_f32_16x16x32_bf16(af[mi], bfr[ni], acc[mi][ni], 0, 0, 0);
    }

    // ---- runtime self-calibration of the C/D lane mapping (2 probe MFMAs).
    // P1: A[m][k]=m, B=1  -> D[m][n]=32m   (tells each (lane,reg) its row)
    // P2: A=1, B[k][n]=n  -> D[m][n]=32n   (tells each (lane,reg) its col)
    // Correct for ANY consistent A/B/C lane permutation of the HW.
    int myrow[4], mycol[4];
    {
        short8 pidx, pone;
        const short rv = (short)f2bf((float)lrow);   // exact for 0..15
        #pragma unroll
        for (int j = 0; j < 8; ++j) { pidx[j] = rv; pone[j] = (short)0x3f80; }
        floatx4 z = {};
        floatx4 p1 = __builtin_amdgcn_mfma_f32_16x16x32_bf16(pidx, pone, z, 0, 0, 0);
        floatx4 p2 = __builtin_amdgcn_mfma_f32_16x16x32_bf16(pone, pidx, z, 0, 0, 0);
        #pragma unroll
        for (int r = 0; r < 4; ++r) {
            myrow[r] = ((int)(p1[r] * 0.03125f + 0.5f)) & 15;
            mycol[r] = ((int)(p2[r] * 0.03125f + 0.5f)) & 15;
        }
    }

    // ---- epilogue: f32 stores at calibrated positions
    const int rbase = bm * BM + wm;
    const int cbase = bn * BN + wn;
    #pragma unroll
    for (int mi = 0; mi < 4; ++mi)
        #pragma unroll
        for (int ni = 0; ni < 4; ++ni)
            #pragma unroll
            for (int r = 0; r < 4; ++r) {
                const int row = rbase + mi * 16 + myrow[r];
                const int col = cbase + ni * 16 + mycol[r];
                out[(size_t)row * N_TOT + col] = acc[mi][ni][r];
            }
}

extern "C" void kernel_launch(void* const* d_in, const int* in_sizes, int n_in,
                              void* d_out, int out_size, void* d_ws, size_t ws_size,
                              hipStream_t stream)
{
    const float* tag  = (const float*)d_in[0];
    const float* wa   = (const float*)d_in[1];
    const float* wb   = (const float*)d_in[2];
    const float* wc   = (const float*)d_in[3];
    const float* bias = (const float*)d_in[4];
    const float* iw   = (const float*)d_in[5];
    const float* ib   = (const float*)d_in[6];
    float* out = (float*)d_out;

    dim3 grid(N_TOT / BN, M_TOT / BM);
    gemm_shared_w<<<grid, 256, 0, stream>>>(wa, wc, wb, tag, out);

    // individual_weight -> rows 8192..10239 (pure f32 copy)
    hipMemcpyAsync(out + (size_t)M_TOT * N_TOT, iw,
                   (size_t)2048 * 2048 * sizeof(float), hipMemcpyDeviceToDevice, stream);

    // bias tail
    const size_t btail = (size_t)(M_TOT + 2048) * N_TOT;
    hipMemcpyAsync(out + btail, bias, 8192 * sizeof(float), hipMemcpyDeviceToDevice, stream);
    hipMemcpyAsync(out + btail + 8192, ib, 2048 * sizeof(float), hipMemcpyDeviceToDevice, stream);
}

// Round 10
// 135.593 us; speedup vs baseline: 1.1911x; 1.1911x over previous
//
#include <hip/hip_runtime.h>
#include <hip/hip_bf16.h>

// s[256] = weight_b @ tag ; shared_w = (Wa * s) @ Wc -> out rows 0..8191 (f32)
// rows 8192..10239 = individual_weight; tail: bias[8192], individual_bias[2048]
// Pipeline: prep_a (bf16(Wa*s) -> ws), prep_bt (bf16(Wc^T) -> ws),
//           gemm_bf (m97-style: global_load_lds, dbuf LDS, 1 barrier/iter),
//           copy_tail (compute-engine copy; SDMA memcpy was ~97us of round-5's 161us).

typedef __attribute__((ext_vector_type(8))) short short8;
typedef __attribute__((ext_vector_type(4))) float floatx4;

#define M_TOT 8192
#define N_TOT 2048
#define K_TOT 256
#define BM 128
#define BN 128
#define BK 32
#define NKT (K_TOT / BK)   // 8

__device__ inline ushort f2bf(float x) {
    union { float f; unsigned u; } v; v.f = x;
    unsigned r = v.u + 0x7fffu + ((v.u >> 16) & 1u);   // RNE
    return (ushort)(r >> 16);
}

__device__ inline void gl_lds16(const void* g, void* l) {
    // Direct C-style casts => clang addrspacecast (NOT inttoptr: integer
    // round-trip would truncate the flat LDS aperture address — wrong).
    __builtin_amdgcn_global_load_lds(
        (const __attribute__((address_space(1))) void*)g,
        (__attribute__((address_space(3))) void*)l,
        16, 0, 0);
}

// ---- prep A: a_bf[m][k] = bf16(Wa[m][k] * s[k]), [8192][256] ----
__global__ __launch_bounds__(256)
void prep_a(const float* __restrict__ Wa, const float* __restrict__ Wb,
            const float* __restrict__ tag, ushort* __restrict__ a_bf)
{
    __shared__ float s_sm[K_TOT];
    const int tid = threadIdx.x;
    {
        float sv = 0.f;
        const float* wb = Wb + tid * 20;
        #pragma unroll
        for (int j = 0; j < 20; ++j) sv += wb[j] * tag[j];
        s_sm[tid] = sv;
    }
    __syncthreads();
    const int sk = (tid * 4) & (K_TOT - 1);          // idx % 256 is constant per thread
    const float4 sv4 = *reinterpret_cast<const float4*>(&s_sm[sk]);
    const size_t base = (size_t)blockIdx.x * 8192;   // 256 blocks x 8192 elems
    #pragma unroll
    for (int r = 0; r < 8; ++r) {
        const size_t idx = base + r * 1024 + tid * 4;
        const float4 a = *reinterpret_cast<const float4*>(Wa + idx);
        ushort4 p;
        p.x = f2bf(a.x * sv4.x); p.y = f2bf(a.y * sv4.y);
        p.z = f2bf(a.z * sv4.z); p.w = f2bf(a.w * sv4.w);
        *reinterpret_cast<ushort4*>(a_bf + idx) = p;
    }
}

// ---- prep B^T: bt[n][k] = bf16(Wc[k][n]), [2048][256] ----
__global__ __launch_bounds__(256)
void prep_bt(const float* __restrict__ Wc, ushort* __restrict__ bt)
{
    __shared__ float T[64][68];                      // +4 pad: conflict-light col reads
    const int k0 = blockIdx.x * 64;                  // 4
    const int n0 = blockIdx.y * 64;                  // 32
    const int tid = threadIdx.x;
    const int tc = tid & 15, tr = tid >> 4;
    #pragma unroll
    for (int rr = 0; rr < 4; ++rr) {
        const int k = tr * 4 + rr;
        const float4 v = *reinterpret_cast<const float4*>(Wc + (size_t)(k0 + k) * N_TOT + n0 + tc * 4);
        T[k][tc * 4 + 0] = v.x; T[k][tc * 4 + 1] = v.y;
        T[k][tc * 4 + 2] = v.z; T[k][tc * 4 + 3] = v.w;
    }
    __syncthreads();
    const int n  = tid >> 2;                         // 0..63
    const int kq = (tid & 3) * 16;                   // 0,16,32,48
    #pragma unroll
    for (int q = 0; q < 4; ++q) {
        const int kk = kq + q * 4;
        ushort4 p;
        p.x = f2bf(T[kk + 0][n]); p.y = f2bf(T[kk + 1][n]);
        p.z = f2bf(T[kk + 2][n]); p.w = f2bf(T[kk + 3][n]);
        *reinterpret_cast<ushort4*>(bt + (size_t)(n0 + n) * K_TOT + k0 + kk) = p;
    }
}

// ---- GEMM: out[0..8192)[0..2048) = A_bf @ B^T_bf, f32 out ----
__global__ __launch_bounds__(256)
void gemm_bf(const ushort* __restrict__ a_bf, const ushort* __restrict__ bt,
             float* __restrict__ out)
{
    __shared__ ushort Abuf[2][BM * BK];   // [128][32] bf16 linear (64B rows)
    __shared__ ushort Bbuf[2][BN * BK];

    const int tid = threadIdx.x;
    // XCD-aware swizzle: 1024 blocks, 8 XCDs, 128 contiguous per XCD
    // -> bm in [x*8, x*8+8): 8 A-panels + all of B (1.5MB bf16) L2-resident per XCD.
    const int bid = blockIdx.x;
    const int swz = (bid & 7) * 128 + (bid >> 3);
    const int bn = swz & 15;
    const int bm = swz >> 4;

    const int lane = tid & 63;
    const int wave = tid >> 6;
    const int wm = (wave >> 1) * 64;
    const int wn = (wave & 1) * 64;
    const int lrow = lane & 15;
    const int lk   = (lane >> 4) * 8;

    // staging: chunk c (16B) -> row c>>2, slot c&3; lane-linear LDS dest
    const int c0 = tid, c1 = tid + 256;
    const ushort* Ag = a_bf + (size_t)(bm * BM) * K_TOT;
    const ushort* Bg = bt   + (size_t)(bn * BN) * K_TOT;

    floatx4 acc[4][4] = {};
    int cur = 0;

    #define STAGE(buf, kt)                                                          \
        do {                                                                        \
            gl_lds16(Ag + (size_t)(c0 >> 2) * K_TOT + (kt) * BK + (c0 & 3) * 8,     \
                     &Abuf[buf][c0 * 8]);                                           \
            gl_lds16(Ag + (size_t)(c1 >> 2) * K_TOT + (kt) * BK + (c1 & 3) * 8,     \
                     &Abuf[buf][c1 * 8]);                                           \
            gl_lds16(Bg + (size_t)(c0 >> 2) * K_TOT + (kt) * BK + (c0 & 3) * 8,     \
                     &Bbuf[buf][c0 * 8]);                                           \
            gl_lds16(Bg + (size_t)(c1 >> 2) * K_TOT + (kt) * BK + (c1 & 3) * 8,     \
                     &Bbuf[buf][c1 * 8]);                                           \
        } while (0)

    STAGE(0, 0);
    __syncthreads();   // drains vmcnt(0): buf0 fully written by all waves

    for (int kt = 0; kt < NKT; ++kt) {
        if (kt + 1 < NKT) STAGE(cur ^ 1, kt + 1);    // issue next tile, hide under compute

        short8 af[4], bfr[4];
        #pragma unroll
        for (int i = 0; i < 4; ++i)
            af[i] = *reinterpret_cast<const short8*>(&Abuf[cur][(wm + i * 16 + lrow) * BK + lk]);
        #pragma unroll
        for (int i = 0; i < 4; ++i)
            bfr[i] = *reinterpret_cast<const short8*>(&Bbuf[cur][(wn + i * 16 + lrow) * BK + lk]);

        #pragma unroll
        for (int mi = 0; mi < 4; ++mi)
            #pragma unroll
            for (int ni = 0; ni < 4; ++ni)
                acc[mi][ni] = __builtin_amdgcn_mfma_f32_16x16x32_bf16(af[mi], bfr[ni], acc[mi][ni], 0, 0, 0);

        __syncthreads();   // reads of cur done + next-tile loads drained (vmcnt 0)
        cur ^= 1;
    }
    #undef STAGE

    // ---- runtime self-calibration of C/D lane mapping (verified passing r5) ----
    int myrow[4], mycol[4];
    {
        short8 pidx, pone;
        const short rv = (short)f2bf((float)lrow);
        #pragma unroll
        for (int j = 0; j < 8; ++j) { pidx[j] = rv; pone[j] = (short)0x3f80; }
        floatx4 z = {};
        floatx4 p1 = __builtin_amdgcn_mfma_f32_16x16x32_bf16(pidx, pone, z, 0, 0, 0);
        floatx4 p2 = __builtin_amdgcn_mfma_f32_16x16x32_bf16(pone, pidx, z, 0, 0, 0);
        #pragma unroll
        for (int r = 0; r < 4; ++r) {
            myrow[r] = ((int)(p1[r] * 0.03125f + 0.5f)) & 15;
            mycol[r] = ((int)(p2[r] * 0.03125f + 0.5f)) & 15;
        }
    }

    const int rbase = bm * BM + wm;
    const int cbase = bn * BN + wn;
    #pragma unroll
    for (int mi = 0; mi < 4; ++mi)
        #pragma unroll
        for (int ni = 0; ni < 4; ++ni)
            #pragma unroll
            for (int r = 0; r < 4; ++r) {
                const int row = rbase + mi * 16 + myrow[r];
                const int col = cbase + ni * 16 + mycol[r];
                out[(size_t)row * N_TOT + col] = acc[mi][ni][r];
            }
}

// ---- tail: compute-engine copies (NOT SDMA) ----
__global__ __launch_bounds__(256)
void copy_tail(const float* __restrict__ iw, const float* __restrict__ bias,
               const float* __restrict__ ib, float* __restrict__ out)
{
    const int tid = threadIdx.x;
    const int b = blockIdx.x;
    if (b < 1024) {
        // individual_weight: 4,194,304 f32 = 1024 blocks x 256 thr x 4 float4
        float* dst = out + (size_t)M_TOT * N_TOT;
        #pragma unroll
        for (int r = 0; r < 4; ++r) {
            const size_t v = (size_t)b * 1024 + r * 256 + tid;
            reinterpret_cast<float4*>(dst)[v] = reinterpret_cast<const float4*>(iw)[v];
        }
    } else if (b == 1024) {
        float* dst = out + (size_t)(M_TOT + 2048) * N_TOT;
        #pragma unroll
        for (int r = 0; r < 8; ++r) {
            const size_t v = r * 256 + tid;          // 2048 float4 = 8192 f32
            reinterpret_cast<float4*>(dst)[v] = reinterpret_cast<const float4*>(bias)[v];
        }
    } else {
        float* dst = out + (size_t)(M_TOT + 2048) * N_TOT + 8192;
        #pragma unroll
        for (int r = 0; r < 2; ++r) {
            const size_t v = r * 256 + tid;          // 512 float4 = 2048 f32
            reinterpret_cast<float4*>(dst)[v] = reinterpret_cast<const float4*>(ib)[v];
        }
    }
}

extern "C" void kernel_launch(void* const* d_in, const int* in_sizes, int n_in,
                              void* d_out, int out_size, void* d_ws, size_t ws_size,
                              hipStream_t stream)
{
    const float* tag  = (const float*)d_in[0];
    const float* wa   = (const float*)d_in[1];
    const float* wb   = (const float*)d_in[2];
    const float* wc   = (const float*)d_in[3];
    const float* bias = (const float*)d_in[4];
    const float* iw   = (const float*)d_in[5];
    const float* ib   = (const float*)d_in[6];
    float* out = (float*)d_out;

    ushort* a_bf = (ushort*)d_ws;                          // 4 MB
    ushort* bt   = (ushort*)d_ws + (size_t)M_TOT * K_TOT;  // 1 MB

    prep_a<<<256, 256, 0, stream>>>(wa, wb, tag, a_bf);
    prep_bt<<<dim3(4, 32), 256, 0, stream>>>(wc, bt);
    gemm_bf<<<1024, 256, 0, stream>>>(a_bf, bt, out);
    copy_tail<<<1026, 256, 0, stream>>>(iw, bias, ib, out);
}

// Round 11
// 129.119 us; speedup vs baseline: 1.2508x; 1.0501x over previous
//
#include <hip/hip_runtime.h>
#include <hip/hip_bf16.h>

// s[256] = weight_b @ tag ; shared_w = (Wa * s) @ Wc -> out rows 0..8191 (f32)
// rows 8192..10239 = individual_weight; tail: bias[8192], individual_bias[2048]
// r10 analysis: dur includes TWO ~51us harness poison fills (out+ws, 335MB @6.5TB/s)
// => our 4 kernels were ~33.6us. This round: fuse to 2 dispatches, widen prep_a.
// GEMM path byte-identical to the r10 PASS.

typedef __attribute__((ext_vector_type(8))) short short8;
typedef __attribute__((ext_vector_type(4))) float floatx4;

#define M_TOT 8192
#define N_TOT 2048
#define K_TOT 256
#define BM 128
#define BN 128
#define BK 32
#define NKT (K_TOT / BK)   // 8

__device__ inline ushort f2bf(float x) {
    union { float f; unsigned u; } v; v.f = x;
    unsigned r = v.u + 0x7fffu + ((v.u >> 16) & 1u);   // RNE
    return (ushort)(r >> 16);
}

__device__ inline void gl_lds16(const void* g, void* l) {
    // Direct C-style casts => clang addrspacecast (NOT inttoptr).
    __builtin_amdgcn_global_load_lds(
        (const __attribute__((address_space(1))) void*)g,
        (__attribute__((address_space(3))) void*)l,
        16, 0, 0);
}

// ---- fused prep: blocks [0,512) convert A, blocks [512,640) transpose B ----
__global__ __launch_bounds__(256)
void prep(const float* __restrict__ Wa, const float* __restrict__ Wb,
          const float* __restrict__ tag, const float* __restrict__ Wc,
          ushort* __restrict__ a_bf, ushort* __restrict__ bt)
{
    __shared__ float s_sm[K_TOT];
    __shared__ float T[64][68];          // +4 pad
    const int tid = threadIdx.x;
    const int bid = blockIdx.x;

    if (bid < 512) {
        // a_bf[m][k] = bf16(Wa[m][k] * s[k]); 512 blocks x 4096 elems
        {
            float sv = 0.f;
            const float* wb = Wb + tid * 20;
            #pragma unroll
            for (int j = 0; j < 20; ++j) sv += wb[j] * tag[j];
            s_sm[tid] = sv;
        }
        __syncthreads();
        const int sk = (tid * 4) & (K_TOT - 1);
        const float4 sv4 = *reinterpret_cast<const float4*>(&s_sm[sk]);
        const size_t base = (size_t)bid * 4096;
        #pragma unroll
        for (int r = 0; r < 4; ++r) {
            const size_t idx = base + r * 1024 + tid * 4;
            const float4 a = *reinterpret_cast<const float4*>(Wa + idx);
            ushort4 p;
            p.x = f2bf(a.x * sv4.x); p.y = f2bf(a.y * sv4.y);
            p.z = f2bf(a.z * sv4.z); p.w = f2bf(a.w * sv4.w);
            *reinterpret_cast<ushort4*>(a_bf + idx) = p;
        }
    } else {
        // bt[n][k] = bf16(Wc[k][n]); 128 blocks of 64x64 tiles
        const int bb = bid - 512;
        const int k0 = (bb & 3) * 64;
        const int n0 = (bb >> 2) * 64;
        const int tc = tid & 15, tr = tid >> 4;
        #pragma unroll
        for (int rr = 0; rr < 4; ++rr) {
            const int k = tr * 4 + rr;
            const float4 v = *reinterpret_cast<const float4*>(Wc + (size_t)(k0 + k) * N_TOT + n0 + tc * 4);
            T[k][tc * 4 + 0] = v.x; T[k][tc * 4 + 1] = v.y;
            T[k][tc * 4 + 2] = v.z; T[k][tc * 4 + 3] = v.w;
        }
        __syncthreads();
        const int n  = tid >> 2;
        const int kq = (tid & 3) * 16;
        #pragma unroll
        for (int q = 0; q < 4; ++q) {
            const int kk = kq + q * 4;
            ushort4 p;
            p.x = f2bf(T[kk + 0][n]); p.y = f2bf(T[kk + 1][n]);
            p.z = f2bf(T[kk + 2][n]); p.w = f2bf(T[kk + 3][n]);
            *reinterpret_cast<ushort4*>(bt + (size_t)(n0 + n) * K_TOT + k0 + kk) = p;
        }
    }
}

// ---- main: blocks [0,1024) GEMM (identical to r10 PASS), [1024,2050) copy ----
__global__ __launch_bounds__(256)
void gemm_plus(const ushort* __restrict__ a_bf, const ushort* __restrict__ bt,
               const float* __restrict__ iw, const float* __restrict__ bias,
               const float* __restrict__ ib, float* __restrict__ out)
{
    __shared__ ushort Abuf[2][BM * BK];   // [128][32] bf16 linear (64B rows)
    __shared__ ushort Bbuf[2][BN * BK];

    const int tid = threadIdx.x;
    const int bid0 = blockIdx.x;

    if (bid0 >= 1024) {
        // ---- tail copies (compute engine) ----
        const int b = bid0 - 1024;
        if (b < 1024) {
            float* dst = out + (size_t)M_TOT * N_TOT;
            #pragma unroll
            for (int r = 0; r < 4; ++r) {
                const size_t v = (size_t)b * 1024 + r * 256 + tid;
                reinterpret_cast<float4*>(dst)[v] = reinterpret_cast<const float4*>(iw)[v];
            }
        } else if (b == 1024) {
            float* dst = out + (size_t)(M_TOT + 2048) * N_TOT;
            #pragma unroll
            for (int r = 0; r < 8; ++r) {
                const size_t v = r * 256 + tid;
                reinterpret_cast<float4*>(dst)[v] = reinterpret_cast<const float4*>(bias)[v];
            }
        } else {
            float* dst = out + (size_t)(M_TOT + 2048) * N_TOT + 8192;
            #pragma unroll
            for (int r = 0; r < 2; ++r) {
                const size_t v = r * 256 + tid;
                reinterpret_cast<float4*>(dst)[v] = reinterpret_cast<const float4*>(ib)[v];
            }
        }
        return;
    }

    // ---- GEMM (byte-identical structure to r10 PASS) ----
    const int bid = bid0;
    const int swz = (bid & 7) * 128 + (bid >> 3);   // 1024 % 8 == 0: bijective
    const int bn = swz & 15;
    const int bm = swz >> 4;

    const int lane = tid & 63;
    const int wave = tid >> 6;
    const int wm = (wave >> 1) * 64;
    const int wn = (wave & 1) * 64;
    const int lrow = lane & 15;
    const int lk   = (lane >> 4) * 8;

    const int c0 = tid, c1 = tid + 256;
    const ushort* Ag = a_bf + (size_t)(bm * BM) * K_TOT;
    const ushort* Bg = bt   + (size_t)(bn * BN) * K_TOT;

    floatx4 acc[4][4] = {};
    int cur = 0;

    #define STAGE(buf, kt)                                                          \
        do {                                                                        \
            gl_lds16(Ag + (size_t)(c0 >> 2) * K_TOT + (kt) * BK + (c0 & 3) * 8,     \
                     &Abuf[buf][c0 * 8]);                                           \
            gl_lds16(Ag + (size_t)(c1 >> 2) * K_TOT + (kt) * BK + (c1 & 3) * 8,     \
                     &Abuf[buf][c1 * 8]);                                           \
            gl_lds16(Bg + (size_t)(c0 >> 2) * K_TOT + (kt) * BK + (c0 & 3) * 8,     \
                     &Bbuf[buf][c0 * 8]);                                           \
            gl_lds16(Bg + (size_t)(c1 >> 2) * K_TOT + (kt) * BK + (c1 & 3) * 8,     \
                     &Bbuf[buf][c1 * 8]);                                           \
        } while (0)

    STAGE(0, 0);
    __syncthreads();

    for (int kt = 0; kt < NKT; ++kt) {
        if (kt + 1 < NKT) STAGE(cur ^ 1, kt + 1);

        short8 af[4], bfr[4];
        #pragma unroll
        for (int i = 0; i < 4; ++i)
            af[i] = *reinterpret_cast<const short8*>(&Abuf[cur][(wm + i * 16 + lrow) * BK + lk]);
        #pragma unroll
        for (int i = 0; i < 4; ++i)
            bfr[i] = *reinterpret_cast<const short8*>(&Bbuf[cur][(wn + i * 16 + lrow) * BK + lk]);

        #pragma unroll
        for (int mi = 0; mi < 4; ++mi)
            #pragma unroll
            for (int ni = 0; ni < 4; ++ni)
                acc[mi][ni] = __builtin_amdgcn_mfma_f32_16x16x32_bf16(af[mi], bfr[ni], acc[mi][ni], 0, 0, 0);

        __syncthreads();
        cur ^= 1;
    }
    #undef STAGE

    // runtime self-calibration of C/D lane mapping (verified r5/r10)
    int myrow[4], mycol[4];
    {
        short8 pidx, pone;
        const short rv = (short)f2bf((float)lrow);
        #pragma unroll
        for (int j = 0; j < 8; ++j) { pidx[j] = rv; pone[j] = (short)0x3f80; }
        floatx4 z = {};
        floatx4 p1 = __builtin_amdgcn_mfma_f32_16x16x32_bf16(pidx, pone, z, 0, 0, 0);
        floatx4 p2 = __builtin_amdgcn_mfma_f32_16x16x32_bf16(pone, pidx, z, 0, 0, 0);
        #pragma unroll
        for (int r = 0; r < 4; ++r) {
            myrow[r] = ((int)(p1[r] * 0.03125f + 0.5f)) & 15;
            mycol[r] = ((int)(p2[r] * 0.03125f + 0.5f)) & 15;
        }
    }

    const int rbase = bm * BM + wm;
    const int cbase = bn * BN + wn;
    #pragma unroll
    for (int mi = 0; mi < 4; ++mi)
        #pragma unroll
        for (int ni = 0; ni < 4; ++ni)
            #pragma unroll
            for (int r = 0; r < 4; ++r) {
                const int row = rbase + mi * 16 + myrow[r];
                const int col = cbase + ni * 16 + mycol[r];
                out[(size_t)row * N_TOT + col] = acc[mi][ni][r];
            }
}

extern "C" void kernel_launch(void* const* d_in, const int* in_sizes, int n_in,
                              void* d_out, int out_size, void* d_ws, size_t ws_size,
                              hipStream_t stream)
{
    const float* tag  = (const float*)d_in[0];
    const float* wa   = (const float*)d_in[1];
    const float* wb   = (const float*)d_in[2];
    const float* wc   = (const float*)d_in[3];
    const float* bias = (const float*)d_in[4];
    const float* iw   = (const float*)d_in[5];
    const float* ib   = (const float*)d_in[6];
    float* out = (float*)d_out;

    ushort* a_bf = (ushort*)d_ws;                          // 4 MB
    ushort* bt   = (ushort*)d_ws + (size_t)M_TOT * K_TOT;  // 1 MB

    prep<<<640, 256, 0, stream>>>(wa, wb, tag, wc, a_bf, bt);
    gemm_plus<<<2050, 256, 0, stream>>>(a_bf, bt, iw, bias, ib, out);
}